// Round 3
// baseline (328.471 us; speedup 1.0000x reference)
//
#include <hip/hip_runtime.h>
#include <hip/hip_bf16.h>
#include <math.h>

#define B   256
#define IU  8
#define IC  1152
#define NU  10
#define US  16

// ---------------- s pass v2 ----------------
// s[b,d,u] = sum_{c,i} cT[d,c] * W[c,d,u,i] * x[b,i,c]
// grid = 8 b-tiles (BT=32, NB=2/thread) x NC c-chunks (CCH per chunk).
// All 20 W float4 loads per cc batched into regs (MLP), x via padded LDS.
template<int CCH>
__global__ __launch_bounds__(256, 3) void s_pass(const float* __restrict__ x,
                                                 const float* __restrict__ W,
                                                 const float* __restrict__ cT,
                                                 float* __restrict__ sp,
                                                 float scale) {
    constexpr int CCHP = CCH + 1;                 // pad -> conflict-free xs reads
    __shared__ float xs[IU * 32 * CCHP];          // [i][bl][ccp]
    __shared__ float cl[NU][CCH];
    const int tid = threadIdx.x;
    const int bt = blockIdx.x & 7;
    const int ch = blockIdx.x >> 3;
    const int b0 = bt * 32, c0 = ch * CCH;

    for (int idx = tid; idx < IU * 32 * CCH; idx += 256) {
        int cc = idx % CCH;
        int r = idx / CCH;
        int bl = r & 31;
        int i = r >> 5;
        xs[(i * 32 + bl) * CCHP + cc] = x[((size_t)(b0 + bl) * IU + i) * IC + c0 + cc];
    }
    for (int idx = tid; idx < NU * CCH; idx += 256) {
        int d = idx / CCH, cc = idx % CCH;
        cl[d][cc] = cT ? cT[d * IC + c0 + cc] : 1.0f;
    }
    __syncthreads();

    const int uq = tid & 15;
    const int bq = tid >> 4;

    float acc[NU][2];
#pragma unroll
    for (int d = 0; d < NU; d++) { acc[d][0] = 0.0f; acc[d][1] = 0.0f; }

    for (int cc = 0; cc < CCH; cc++) {
        float xv0[IU], xv1[IU];
#pragma unroll
        for (int i = 0; i < IU; i++) {
            xv0[i] = xs[(i * 32 + bq * 2 + 0) * CCHP + cc];
            xv1[i] = xs[(i * 32 + bq * 2 + 1) * CCHP + cc];
        }
        const float* wp = W + (size_t)(c0 + cc) * (NU * US * IU) + uq * IU;
        float4 wa[NU], wb[NU];
#pragma unroll
        for (int d = 0; d < NU; d++) {
            wa[d] = *(const float4*)(wp + d * (US * IU));
            wb[d] = *(const float4*)(wp + d * (US * IU) + 4);
        }
#pragma unroll
        for (int d = 0; d < NU; d++) {
            float cc_ = cl[d][cc];
            float d0 = wa[d].x * xv0[0] + wa[d].y * xv0[1] + wa[d].z * xv0[2] + wa[d].w * xv0[3]
                     + wb[d].x * xv0[4] + wb[d].y * xv0[5] + wb[d].z * xv0[6] + wb[d].w * xv0[7];
            float d1 = wa[d].x * xv1[0] + wa[d].y * xv1[1] + wa[d].z * xv1[2] + wa[d].w * xv1[3]
                     + wb[d].x * xv1[4] + wb[d].y * xv1[5] + wb[d].z * xv1[6] + wb[d].w * xv1[7];
            acc[d][0] += cc_ * d0;
            acc[d][1] += cc_ * d1;
        }
    }
#pragma unroll
    for (int bb = 0; bb < 2; bb++) {
        int b = b0 + bq * 2 + bb;
#pragma unroll
        for (int d = 0; d < NU; d++)
            sp[(((size_t)ch * B + b) * NU + d) * US + uq] = acc[d][bb] * scale;
    }
}

// ---------------- squash ----------------
__global__ __launch_bounds__(192) void squash_k(const float* __restrict__ sp,
                                                float* __restrict__ vout, int nc) {
    __shared__ float smag[NU * US];
    const int b = blockIdx.x;
    const int tid = threadIdx.x;
    const int d = tid >> 4, uq = tid & 15;
    float s = 0.0f;
    if (d < NU) {
        for (int chp = 0; chp < nc; chp++)
            s += sp[(((size_t)chp * B + b) * NU + d) * US + uq];
        smag[d * US + uq] = s * s;
    }
    __syncthreads();
    if (d < NU) {
        float msq = 0.0f;
#pragma unroll
        for (int dd = 0; dd < NU; dd++) msq += smag[dd * US + uq];
        float f = msq / ((1.0f + msq) * sqrtf(msq));
        vout[((size_t)b * NU + d) * US + uq] = s * f;
    }
}

// ---------------- agree pass v2 ----------------
// agree[c,d] = sum_{b,u} (sum_i W[c,d,u,i]*x[b,i,c]) * v[b,d,u]
// grid 720 = 36 c-tiles(32) x 10 d x 2 b-halves(128). Lane owns c and keeps
// W[c,d,:,:] (128 floats) in regs -> per-b cost: 8 ds_read_b32 + 4 float4 v-loads
// vs 144 FMA (VALU-bound). Partials ap[bh][d][c], bh=2.
__global__ __launch_bounds__(256, 2) void agree_k(const float* __restrict__ x,
                                                  const float* __restrict__ W,
                                                  const float* __restrict__ v,
                                                  float* __restrict__ ap) {
    __shared__ float wst[32 * 132];   // [c][132] (pad 4; one-time 4-way ok)
    __shared__ float xs[32 * IU * 32]; // [bl][i][c] per 32-b round, 32 KB
    __shared__ float red[8 * 33];
    const int tid = threadIdx.x;
    const int bx = blockIdx.x;
    const int ct = bx % 36;
    const int r0 = bx / 36;
    const int d = r0 % NU;
    const int bh = r0 / NU;
    const int c0 = ct * 32, bbase = bh * 128;

    for (int idx = tid; idx < 32 * 128; idx += 256) {
        int c = idx >> 7, k = idx & 127;
        wst[c * 132 + k] = W[(size_t)(c0 + c) * (NU * US * IU) + d * US * IU + k];
    }
    __syncthreads();

    const int cl_ = tid & 31;
    const int bq = tid >> 5;

    float w[US][IU];
#pragma unroll
    for (int u = 0; u < US; u++)
#pragma unroll
        for (int i = 0; i < IU; i++)
            w[u][i] = wst[cl_ * 132 + u * IU + i];

    float acc = 0.0f;
    for (int r = 0; r < 4; r++) {
        __syncthreads();
        for (int idx = tid; idx < 2048; idx += 256) {   // float4 units
            int cq = idx & 7, i = (idx >> 3) & 7, bl = idx >> 6;
            ((float4*)xs)[idx] =
                *(const float4*)(x + (size_t)(bbase + r * 32 + bl) * (IU * IC) + i * IC + c0 + cq * 4);
        }
        __syncthreads();
#pragma unroll
        for (int bl2 = 0; bl2 < 4; bl2++) {
            int bl = bq * 4 + bl2;
            int gb = bbase + r * 32 + bl;
            float xv[IU];
#pragma unroll
            for (int i = 0; i < IU; i++) xv[i] = xs[(bl * IU + i) * 32 + cl_];
            const float4* vp = (const float4*)(v + ((size_t)gb * NU + d) * US);
            float4 v0 = vp[0], v1 = vp[1], v2 = vp[2], v3 = vp[3];
            const float vf[US] = {v0.x, v0.y, v0.z, v0.w, v1.x, v1.y, v1.z, v1.w,
                                  v2.x, v2.y, v2.z, v2.w, v3.x, v3.y, v3.z, v3.w};
            float part = 0.0f;
#pragma unroll
            for (int u = 0; u < US; u++) {
                float uh = 0.0f;
#pragma unroll
                for (int i = 0; i < IU; i++) uh += w[u][i] * xv[i];
                part += uh * vf[u];
            }
            acc += part;
        }
    }
    red[bq * 33 + cl_] = acc;
    __syncthreads();
    if (tid < 32) {
        float s = 0.0f;
#pragma unroll
        for (int g = 0; g < 8; g++) s += red[g * 33 + tid];
        ap[((size_t)bh * NU + d) * IC + c0 + tid] = s;
    }
}

// ---------------- b update + softmax over channels ----------------
__global__ __launch_bounds__(384) void bsm_k(const float* __restrict__ ap,
                                             float* __restrict__ bij,
                                             float* __restrict__ cT,
                                             int first) {
    __shared__ float wred[8];
    __shared__ float bcast;
    const int d = blockIdx.x;
    const int tid = threadIdx.x;
    float bn[3];
    float lmax = -1e30f;
#pragma unroll
    for (int k = 0; k < 3; k++) {
        int c = tid + k * 384;
        float a = ap[(0 * NU + d) * IC + c] + ap[((size_t)1 * NU + d) * IC + c];
        a *= (1.0f / (float)B);
        float bo = first ? 0.0f : bij[d * IC + c];
        bn[k] = bo + a;
        bij[d * IC + c] = bn[k];
        lmax = fmaxf(lmax, bn[k]);
    }
    for (int off = 32; off > 0; off >>= 1) lmax = fmaxf(lmax, __shfl_down(lmax, off, 64));
    const int wid = tid >> 6, lane = tid & 63;
    if (lane == 0) wred[wid] = lmax;
    __syncthreads();
    if (tid == 0) {
        float m = wred[0];
        for (int w_ = 1; w_ < 6; w_++) m = fmaxf(m, wred[w_]);
        bcast = m;
    }
    __syncthreads();
    const float mx = bcast;
    float e[3];
    float lsum = 0.0f;
#pragma unroll
    for (int k = 0; k < 3; k++) { e[k] = expf(bn[k] - mx); lsum += e[k]; }
    for (int off = 32; off > 0; off >>= 1) lsum += __shfl_down(lsum, off, 64);
    if (lane == 0) wred[wid] = lsum;
    __syncthreads();
    if (tid == 0) {
        float s2 = 0.0f;
        for (int w_ = 0; w_ < 6; w_++) s2 += wred[w_];
        bcast = 1.0f / s2;
    }
    __syncthreads();
    const float inv = bcast;
#pragma unroll
    for (int k = 0; k < 3; k++) cT[d * IC + tid + k * 384] = e[k] * inv;
}

extern "C" void kernel_launch(void* const* d_in, const int* in_sizes, int n_in,
                              void* d_out, int out_size, void* d_ws, size_t ws_size,
                              hipStream_t stream) {
    const float* x = (const float*)d_in[0];   // [256, 8, 1152]
    const float* W = (const float*)d_in[1];   // [1, 1152, 10, 16, 8]
    float* out = (float*)d_out;               // [256, 10, 16] fp32

    // Preferred config: NC=96 c-chunks (CCH=12) -> sp needs 15.7 MB.
    const size_t need96 = ((size_t)96 * B * NU * US + B * NU * US + 3 * NU * IC) * 4;
    const bool big = ws_size >= need96;
    const int NC = big ? 96 : 32;

    float* sp  = (float*)d_ws;                       // NC * 256*10*16 floats
    float* v   = sp + (size_t)NC * B * NU * US;      // 40,960
    float* bij = v + (size_t)B * NU * US;            // 11,520  [d][c]
    float* cT  = bij + (size_t)NU * IC;              // 11,520  [d][c]
    float* apg = cT + (size_t)NU * IC;               // 2*10*1152 = 23,040

    const float inv_ic = 1.0f / (float)IC;
    const int grid_s = 8 * NC;

    // iteration 1 (c uniform = 1/1152)
    if (big) s_pass<12><<<grid_s, 256, 0, stream>>>(x, W, nullptr, sp, inv_ic);
    else     s_pass<36><<<grid_s, 256, 0, stream>>>(x, W, nullptr, sp, inv_ic);
    squash_k<<<B, 192, 0, stream>>>(sp, v, NC);
    agree_k<<<720, 256, 0, stream>>>(x, W, v, apg);
    bsm_k<<<NU, 384, 0, stream>>>(apg, bij, cT, 1);
    // iteration 2
    if (big) s_pass<12><<<grid_s, 256, 0, stream>>>(x, W, cT, sp, 1.0f);
    else     s_pass<36><<<grid_s, 256, 0, stream>>>(x, W, cT, sp, 1.0f);
    squash_k<<<B, 192, 0, stream>>>(sp, v, NC);
    agree_k<<<720, 256, 0, stream>>>(x, W, v, apg);
    bsm_k<<<NU, 384, 0, stream>>>(apg, bij, cT, 0);
    // iteration 3 (agree not needed after final squash)
    if (big) s_pass<12><<<grid_s, 256, 0, stream>>>(x, W, cT, sp, 1.0f);
    else     s_pass<36><<<grid_s, 256, 0, stream>>>(x, W, cT, sp, 1.0f);
    squash_k<<<B, 192, 0, stream>>>(sp, out, NC);
}